// Round 1
// baseline (337.879 us; speedup 1.0000x reference)
//
#include <hip/hip_runtime.h>

#define E_DIM 1024
#define SEQ 1024
#define BATCH 4
#define NHEAD 16
#define DK 64
#define TOK 4096
#define FFN_DIM 4096
#define NQB 8
#define NLAY 4

typedef __attribute__((ext_vector_type(8))) short short8;
typedef __attribute__((ext_vector_type(4))) float f32x4;
typedef unsigned short u16;

__device__ __forceinline__ u16 f2bf(float f) {
  union { float f; unsigned u; } v; v.f = f;
  unsigned r = v.u + 0x7fffu + ((v.u >> 16) & 1u);
  return (u16)(r >> 16);
}

__device__ __forceinline__ void gload_lds16(const u16* g, u16* l) {
  __builtin_amdgcn_global_load_lds((const __attribute__((address_space(1))) unsigned int*)g,
                                   (__attribute__((address_space(3))) unsigned int*)l, 16, 0, 0);
}

// ---------------- casts ----------------
__global__ void cast_kernel(const float* __restrict__ in, u16* __restrict__ out, int n4) {
  int i = blockIdx.x * blockDim.x + threadIdx.x;
  int stride = gridDim.x * blockDim.x;
  for (; i < n4; i += stride) {
    float4 v = ((const float4*)in)[i];
    ushort4 o;
    o.x = f2bf(v.x); o.y = f2bf(v.y); o.z = f2bf(v.z); o.w = f2bf(v.w);
    ((ushort4*)out)[i] = o;
  }
}

__global__ void cast4_kernel(const float* __restrict__ a0, const float* __restrict__ a1,
                             const float* __restrict__ a2, const float* __restrict__ a3,
                             u16* __restrict__ out, int n4per) {
  const float* src = blockIdx.z == 0 ? a0 : blockIdx.z == 1 ? a1 : blockIdx.z == 2 ? a2 : a3;
  u16* dst = out + (size_t)blockIdx.z * n4per * 4;
  int i = blockIdx.x * blockDim.x + threadIdx.x;
  int stride = gridDim.x * blockDim.x;
  for (; i < n4per; i += stride) {
    float4 v = ((const float4*)src)[i];
    ushort4 o;
    o.x = f2bf(v.x); o.y = f2bf(v.y); o.z = f2bf(v.z); o.w = f2bf(v.w);
    ((ushort4*)dst)[i] = o;
  }
}

// ---------------- GEMM: C[M,N] = A[M,K] * B[N,K]^T (bf16, fp32 acc) ----------------
// m97 structure: 128x128 tile, BK=32, 256 thr = 4 waves (2x2), wave does 64x64 via 4x4 frags.
template<int F32OUT>
__global__ __launch_bounds__(256) void gemm_bt(
    const u16* __restrict__ A,
    const u16* __restrict__ B0, const u16* __restrict__ B1, const u16* __restrict__ B2,
    void* __restrict__ C0, void* __restrict__ C1, void* __restrict__ C2,
    const float* __restrict__ bias, int K, int N) {
  const u16* B = blockIdx.z == 0 ? B0 : blockIdx.z == 1 ? B1 : B2;
  void* C = blockIdx.z == 0 ? C0 : blockIdx.z == 1 ? C1 : C2;
  __shared__ u16 As[128 * 32];
  __shared__ u16 Bs[128 * 32];
  const int tid = threadIdx.x;
  const int lane = tid & 63;
  const int wid = tid >> 6;
  const int wr = wid >> 1, wc = wid & 1;
  const int lr = lane & 15, lg = lane >> 4;
  const int row0 = blockIdx.y * 128;
  const int col0 = blockIdx.x * 128;
  const int ar = tid >> 2;
  const int ak = (tid & 3) * 8;
  const u16* Ag = A + (size_t)(row0 + ar) * K + ak;
  const u16* Bg = B + (size_t)(col0 + ar) * K + ak;
  u16* AsW = &As[wid * 512];   // wave-uniform LDS base: wave w covers bytes [w*1024, w*1024+1024)
  u16* BsW = &Bs[wid * 512];
  f32x4 acc[4][4];
  const f32x4 fzero = {0.f, 0.f, 0.f, 0.f};
#pragma unroll
  for (int m = 0; m < 4; ++m)
#pragma unroll
    for (int n = 0; n < 4; ++n) acc[m][n] = fzero;
  for (int k0 = 0; k0 < K; k0 += 32) {
    __syncthreads();
    gload_lds16(Ag + k0, AsW);
    gload_lds16(Ag + (size_t)64 * K + k0, AsW + 2048);
    gload_lds16(Bg + k0, BsW);
    gload_lds16(Bg + (size_t)64 * K + k0, BsW + 2048);
    __syncthreads();
    short8 af[4], bfr[4];
#pragma unroll
    for (int m = 0; m < 4; ++m) af[m] = *(const short8*)&As[(wr * 64 + m * 16 + lr) * 32 + lg * 8];
#pragma unroll
    for (int n = 0; n < 4; ++n) bfr[n] = *(const short8*)&Bs[(wc * 64 + n * 16 + lr) * 32 + lg * 8];
#pragma unroll
    for (int m = 0; m < 4; ++m)
#pragma unroll
      for (int n = 0; n < 4; ++n)
        acc[m][n] = __builtin_amdgcn_mfma_f32_16x16x32_bf16(af[m], bfr[n], acc[m][n], 0, 0, 0);
  }
#pragma unroll
  for (int m = 0; m < 4; ++m) {
    const int growb = row0 + wr * 64 + m * 16 + lg * 4;
#pragma unroll
    for (int n = 0; n < 4; ++n) {
      const int gcol = col0 + wc * 64 + n * 16 + lr;
#pragma unroll
      for (int r = 0; r < 4; ++r) {
        size_t idx = (size_t)(growb + r) * N + gcol;
        if (F32OUT) ((float*)C)[idx] = acc[m][n][r] + bias[gcol];
        else ((u16*)C)[idx] = f2bf(acc[m][n][r]);
      }
    }
  }
}

// ---------------- flash attention per (b,h,qblk=64 rows) ----------------
__global__ __launch_bounds__(256) void attn_kernel(
    const u16* __restrict__ qb, const u16* __restrict__ kb, const u16* __restrict__ vb,
    const float* __restrict__ gate, u16* __restrict__ ob) {
  const int qblk = blockIdx.x, h = blockIdx.y, b = blockIdx.z;
  const int tid = threadIdx.x, lane = tid & 63, w = tid >> 6;
  const int lr = lane & 15, lg = lane >> 4;
  // +8 pad (stride 72 elems = 144B) breaks the stride-128B bank conflict on frag reads
  __shared__ u16 Kl[64 * 72];
  __shared__ u16 Vt[64 * 72];
  __shared__ u16 Pl[64 * 72];
  const u16* Qp = qb + (size_t)(b * SEQ + qblk * 64 + w * 16 + lr) * E_DIM + h * DK;
  const short8 aq0 = *(const short8*)&Qp[lg * 8];
  const short8 aq1 = *(const short8*)&Qp[32 + lg * 8];
  f32x4 o[4];
  const f32x4 fzero = {0.f, 0.f, 0.f, 0.f};
#pragma unroll
  for (int n = 0; n < 4; ++n) o[n] = fzero;
  float mrow[4] = {-1e30f, -1e30f, -1e30f, -1e30f};
  float lrow[4] = {0.f, 0.f, 0.f, 0.f};
  for (int kt = 0; kt < 16; ++kt) {
    __syncthreads();
#pragma unroll
    for (int it = 0; it < 2; ++it) {
      int idx = it * 256 + tid;
      int r = idx >> 3, dd = (idx & 7) * 8;
      size_t g = (size_t)(b * SEQ + kt * 64 + r) * E_DIM + h * DK + dd;
      *(short8*)&Kl[r * 72 + dd] = *(const short8*)&kb[g];
      short8 vv = *(const short8*)&vb[g];
#pragma unroll
      for (int j = 0; j < 8; ++j) Vt[(dd + j) * 72 + r] = (u16)vv[j];
    }
    __syncthreads();
    f32x4 s[4];
#pragma unroll
    for (int n = 0; n < 4; ++n) s[n] = fzero;
#pragma unroll
    for (int n = 0; n < 4; ++n) {
      const short8 bk0 = *(const short8*)&Kl[(n * 16 + lr) * 72 + lg * 8];
      const short8 bk1 = *(const short8*)&Kl[(n * 16 + lr) * 72 + 32 + lg * 8];
      s[n] = __builtin_amdgcn_mfma_f32_16x16x32_bf16(aq0, bk0, s[n], 0, 0, 0);
      s[n] = __builtin_amdgcn_mfma_f32_16x16x32_bf16(aq1, bk1, s[n], 0, 0, 0);
    }
    float tm[4];
#pragma unroll
    for (int r = 0; r < 4; ++r) {
      float v = fmaxf(fmaxf(s[0][r], s[1][r]), fmaxf(s[2][r], s[3][r])) * 0.125f;
      v = fmaxf(v, __shfl_xor(v, 1));
      v = fmaxf(v, __shfl_xor(v, 2));
      v = fmaxf(v, __shfl_xor(v, 4));
      v = fmaxf(v, __shfl_xor(v, 8));
      tm[r] = v;
    }
    float alpha[4];
#pragma unroll
    for (int r = 0; r < 4; ++r) {
      float mn = fmaxf(mrow[r], tm[r]);
      alpha[r] = __expf(mrow[r] - mn);
      mrow[r] = mn;
    }
    float ts[4] = {0.f, 0.f, 0.f, 0.f};
#pragma unroll
    for (int n = 0; n < 4; ++n) {
#pragma unroll
      for (int r = 0; r < 4; ++r) {
        float p = __expf(s[n][r] * 0.125f - mrow[r]);
        ts[r] += p;
        Pl[(w * 16 + lg * 4 + r) * 72 + n * 16 + lr] = f2bf(p);
      }
    }
#pragma unroll
    for (int r = 0; r < 4; ++r) {
      float v = ts[r];
      v += __shfl_xor(v, 1);
      v += __shfl_xor(v, 2);
      v += __shfl_xor(v, 4);
      v += __shfl_xor(v, 8);
      lrow[r] = lrow[r] * alpha[r] + v;
    }
#pragma unroll
    for (int n = 0; n < 4; ++n)
#pragma unroll
      for (int r = 0; r < 4; ++r) o[n][r] *= alpha[r];
    const short8 ap0 = *(const short8*)&Pl[(w * 16 + lr) * 72 + lg * 8];
    const short8 ap1 = *(const short8*)&Pl[(w * 16 + lr) * 72 + 32 + lg * 8];
#pragma unroll
    for (int n = 0; n < 4; ++n) {
      const short8 bv0 = *(const short8*)&Vt[(n * 16 + lr) * 72 + lg * 8];
      const short8 bv1 = *(const short8*)&Vt[(n * 16 + lr) * 72 + 32 + lg * 8];
      o[n] = __builtin_amdgcn_mfma_f32_16x16x32_bf16(ap0, bv0, o[n], 0, 0, 0);
      o[n] = __builtin_amdgcn_mfma_f32_16x16x32_bf16(ap1, bv1, o[n], 0, 0, 0);
    }
  }
  const float sg = 1.f / (1.f + __expf(-gate[h]));
#pragma unroll
  for (int n = 0; n < 4; ++n)
#pragma unroll
    for (int r = 0; r < 4; ++r) {
      float v = o[n][r] / lrow[r] * sg;
      size_t row = (size_t)(b * SEQ + qblk * 64 + w * 16 + lg * 4 + r);
      ob[row * E_DIM + h * DK + n * 16 + lr] = f2bf(v);
    }
}

// ---------------- quantum statevector sim (token-independent) + relu_vec ----------------
__device__ __forceinline__ float2 cmul(float2 a, float2 b) {
  return make_float2(a.x * b.x - a.y * b.y, a.x * b.y + a.y * b.x);
}

__global__ __launch_bounds__(256) void quantum_kernel(
    const float* __restrict__ qparams, const float* __restrict__ W1,
    const float* __restrict__ bf1, float* __restrict__ relu_out) {
  __shared__ float2 st[256];
  __shared__ float pr[256];
  __shared__ float evs_s[NQB];
  const int t = threadIdx.x;
  st[t] = make_float2(t == 0 ? 1.f : 0.f, 0.f);
  for (int l = 0; l < NLAY; ++l) {
    for (int q = 0; q < NQB; ++q) {
      const int stride = 128 >> q;   // qubit q = bit (7-q)
      for (int g = 0; g < 3; ++g) {
        const float th = qparams[(l * NQB + q) * 3 + g] * 0.5f;
        const float c = cosf(th), sn = sinf(th);
        float2 g00, g01, g10, g11;
        if (g == 0)      { g00 = make_float2(c, 0.f); g01 = make_float2(0.f, -sn); g10 = g01; g11 = g00; }
        else if (g == 1) { g00 = make_float2(c, 0.f); g01 = make_float2(-sn, 0.f); g10 = make_float2(sn, 0.f); g11 = g00; }
        else             { g00 = make_float2(c, -sn); g01 = make_float2(0.f, 0.f); g10 = g01; g11 = make_float2(c, sn); }
        __syncthreads();
        if (t < 128) {
          const int low = t & (stride - 1);
          const int high = t >> (7 - q);
          const int i0 = (high << (8 - q)) | low;
          const int i1 = i0 + stride;
          const float2 a0 = st[i0], a1 = st[i1];
          float2 n0 = cmul(g00, a0), tmp = cmul(g01, a1);
          n0.x += tmp.x; n0.y += tmp.y;
          float2 n1 = cmul(g10, a0); tmp = cmul(g11, a1);
          n1.x += tmp.x; n1.y += tmp.y;
          st[i0] = n0; st[i1] = n1;
        }
      }
    }
    for (int ci = 0; ci < NQB; ++ci) {
      const int cb = 128 >> ci;
      const int tb = 128 >> ((ci + 1) & 7);
      __syncthreads();
      if ((t & cb) && !(t & tb)) {   // control=1, target=0: swap with partner (disjoint pairs)
        const float2 a = st[t];
        const float2 bb = st[t ^ tb];
        st[t] = bb; st[t ^ tb] = a;
      }
    }
  }
  __syncthreads();
  pr[t] = st[t].x * st[t].x + st[t].y * st[t].y;
  __syncthreads();
  if (t < NQB) {
    const int bit = 128 >> t;
    float s = 0.f;
    for (int i = 0; i < 256; ++i)
      if (i & bit) s += pr[i];
    evs_s[t] = 1.f - 2.f * s;
  }
  __syncthreads();
  for (int j = t; j < FFN_DIM; j += 256) {
    float a = bf1[j];
#pragma unroll
    for (int n = 0; n < NQB; ++n) a += evs_s[n] * W1[j * NQB + n];
    relu_out[j] = fmaxf(a, 0.f);
  }
}

// ---------------- fvec[e] = relu_vec . W2[e,:] + bf2[e]  (wave per row) ----------------
__global__ __launch_bounds__(256) void fvec_kernel(
    const float* __restrict__ W2, const float* __restrict__ bf2,
    const float* __restrict__ relu_vec, float* __restrict__ fvec) {
  const int w = threadIdx.x >> 6, lane = threadIdx.x & 63;
  const int e = blockIdx.x * 4 + w;
  const float* row = W2 + (size_t)e * FFN_DIM;
  float s = 0.f;
  for (int i = lane * 4; i < FFN_DIM; i += 256) {
    const float4 wv = *(const float4*)&row[i];
    const float4 rv = *(const float4*)&relu_vec[i];
    s += wv.x * rv.x + wv.y * rv.y + wv.z * rv.z + wv.w * rv.w;
  }
#pragma unroll
  for (int d = 32; d >= 1; d >>= 1) s += __shfl_down(s, d);
  if (lane == 0) fvec[e] = s + bf2[e];
}

// ---------------- fused: h=LN(x+ao,g1,b1); out=LN(h+fvec,g2,b2) ----------------
__global__ __launch_bounds__(256) void final_ln_kernel(
    const float* __restrict__ x, const float* __restrict__ ao, const float* __restrict__ fvec,
    const float* __restrict__ g1, const float* __restrict__ b1,
    const float* __restrict__ g2, const float* __restrict__ b2, float* __restrict__ out) {
  __shared__ float sm1[8];
  __shared__ float sm2[8];
  const size_t row = blockIdx.x;
  const int tid = threadIdx.x;
  const int w = tid >> 6, lane = tid & 63;
  const float4 xv = *(const float4*)&x[row * E_DIM + tid * 4];
  const float4 av = *(const float4*)&ao[row * E_DIM + tid * 4];
  float v0 = xv.x + av.x, v1 = xv.y + av.y, v2 = xv.z + av.z, v3 = xv.w + av.w;
  float s = v0 + v1 + v2 + v3;
  float ss = v0 * v0 + v1 * v1 + v2 * v2 + v3 * v3;
#pragma unroll
  for (int d = 32; d >= 1; d >>= 1) { s += __shfl_down(s, d); ss += __shfl_down(ss, d); }
  if (lane == 0) { sm1[w * 2] = s; sm1[w * 2 + 1] = ss; }
  __syncthreads();
  s = sm1[0] + sm1[2] + sm1[4] + sm1[6];
  ss = sm1[1] + sm1[3] + sm1[5] + sm1[7];
  const float mean = s * (1.f / 1024.f);
  const float var = ss * (1.f / 1024.f) - mean * mean;
  const float rstd = rsqrtf(var + 1e-5f);
  const float4 g1v = *(const float4*)&g1[tid * 4];
  const float4 b1v = *(const float4*)&b1[tid * 4];
  const float4 fv = *(const float4*)&fvec[tid * 4];
  float z0 = (v0 - mean) * rstd * g1v.x + b1v.x + fv.x;
  float z1 = (v1 - mean) * rstd * g1v.y + b1v.y + fv.y;
  float z2 = (v2 - mean) * rstd * g1v.z + b1v.z + fv.z;
  float z3 = (v3 - mean) * rstd * g1v.w + b1v.w + fv.w;
  float s2 = z0 + z1 + z2 + z3;
  float ss2 = z0 * z0 + z1 * z1 + z2 * z2 + z3 * z3;
#pragma unroll
  for (int d = 32; d >= 1; d >>= 1) { s2 += __shfl_down(s2, d); ss2 += __shfl_down(ss2, d); }
  if (lane == 0) { sm2[w * 2] = s2; sm2[w * 2 + 1] = ss2; }
  __syncthreads();
  s2 = sm2[0] + sm2[2] + sm2[4] + sm2[6];
  ss2 = sm2[1] + sm2[3] + sm2[5] + sm2[7];
  const float mean2 = s2 * (1.f / 1024.f);
  const float var2 = ss2 * (1.f / 1024.f) - mean2 * mean2;
  const float rstd2 = rsqrtf(var2 + 1e-5f);
  const float4 g2v = *(const float4*)&g2[tid * 4];
  const float4 b2v = *(const float4*)&b2[tid * 4];
  float4 ov;
  ov.x = (z0 - mean2) * rstd2 * g2v.x + b2v.x;
  ov.y = (z1 - mean2) * rstd2 * g2v.y + b2v.y;
  ov.z = (z2 - mean2) * rstd2 * g2v.z + b2v.z;
  ov.w = (z3 - mean2) * rstd2 * g2v.w + b2v.w;
  *(float4*)&out[row * E_DIM + tid * 4] = ov;
}

extern "C" void kernel_launch(void* const* d_in, const int* in_sizes, int n_in,
                              void* d_out, int out_size, void* d_ws, size_t ws_size,
                              hipStream_t stream) {
  (void)in_sizes; (void)n_in; (void)out_size; (void)ws_size;
  const float* x       = (const float*)d_in[0];
  const float* Wq      = (const float*)d_in[1];
  const float* Wk      = (const float*)d_in[2];
  const float* Wv      = (const float*)d_in[3];
  const float* Wo      = (const float*)d_in[4];
  const float* bo      = (const float*)d_in[5];
  const float* gate    = (const float*)d_in[6];
  const float* g1      = (const float*)d_in[7];
  const float* b1      = (const float*)d_in[8];
  const float* g2      = (const float*)d_in[9];
  const float* b2      = (const float*)d_in[10];
  // d_in[11] Wi, d_in[12] bi: computed-but-unused in reference -> skipped
  const float* qparams = (const float*)d_in[13];
  const float* W1      = (const float*)d_in[14];
  const float* bf1     = (const float*)d_in[15];
  const float* W2      = (const float*)d_in[16];
  const float* bf2     = (const float*)d_in[17];

  char* ws = (char*)d_ws;
  u16* xb        = (u16*)(ws + 0);          // 8 MB
  u16* wqb       = (u16*)(ws + 8388608);    // 2 MB each
  u16* wkb       = (u16*)(ws + 10485760);
  u16* wvb       = (u16*)(ws + 12582912);
  u16* wob       = (u16*)(ws + 14680064);
  u16* qb        = (u16*)(ws + 16777216);   // 8 MB
  u16* kb        = (u16*)(ws + 25165824);   // 8 MB
  u16* vb        = (u16*)(ws + 33554432);   // 8 MB
  u16* ab        = (u16*)(ws + 41943040);   // 8 MB
  float* ao      = (float*)(ws + 50331648); // 16 MB
  float* relu_vec= (float*)(ws + 67108864); // 16 KB
  float* fvec    = (float*)(ws + 67125248); // 4 KB

  cast_kernel<<<2048, 256, 0, stream>>>(x, xb, TOK * E_DIM / 4);
  cast4_kernel<<<dim3(1024, 1, 4), 256, 0, stream>>>(Wq, Wk, Wv, Wo, wqb, E_DIM * E_DIM / 4);
  quantum_kernel<<<1, 256, 0, stream>>>(qparams, W1, bf1, relu_vec);
  fvec_kernel<<<256, 256, 0, stream>>>(W2, bf2, relu_vec, fvec);
  gemm_bt<0><<<dim3(8, 32, 3), 256, 0, stream>>>(xb, wqb, wkb, wvb, qb, kb, vb, nullptr, E_DIM, E_DIM);
  attn_kernel<<<dim3(16, 16, 4), 256, 0, stream>>>(qb, kb, vb, gate, ab);
  gemm_bt<1><<<dim3(8, 32, 1), 256, 0, stream>>>(ab, wob, wob, wob, ao, ao, ao, bo, E_DIM, E_DIM);
  final_ln_kernel<<<4096, 256, 0, stream>>>(x, ao, fvec, g1, b1, g2, b2, (float*)d_out);
}

// Round 2
// 297.667 us; speedup vs baseline: 1.1351x; 1.1351x over previous
//
#include <hip/hip_runtime.h>

#define E_DIM 1024
#define SEQ 1024
#define BATCH 4
#define NHEAD 16
#define DK 64
#define TOK 4096
#define FFN_DIM 4096
#define NQB 8
#define NLAY 4

typedef __attribute__((ext_vector_type(8))) short short8;
typedef __attribute__((ext_vector_type(4))) float f32x4;
typedef unsigned short u16;
typedef unsigned int u32;

__device__ __forceinline__ u16 f2bf(float f) {
  union { float f; unsigned u; } v; v.f = f;
  unsigned r = v.u + 0x7fffu + ((v.u >> 16) & 1u);
  return (u16)(r >> 16);
}

__device__ __forceinline__ u32 cvtpk_bf16(float lo, float hi) {
  u32 r;
  asm("v_cvt_pk_bf16_f32 %0, %1, %2" : "=v"(r) : "v"(lo), "v"(hi));
  return r;
}

__device__ __forceinline__ void gload_lds16(const u16* g, u16* l) {
  __builtin_amdgcn_global_load_lds((const __attribute__((address_space(1))) unsigned int*)g,
                                   (__attribute__((address_space(3))) unsigned int*)l, 16, 0, 0);
}

// ---------------- casts ----------------
__global__ void cast_kernel(const float* __restrict__ in, u16* __restrict__ out, int n4) {
  int i = blockIdx.x * blockDim.x + threadIdx.x;
  int stride = gridDim.x * blockDim.x;
  for (; i < n4; i += stride) {
    float4 v = ((const float4*)in)[i];
    ushort4 o;
    o.x = f2bf(v.x); o.y = f2bf(v.y); o.z = f2bf(v.z); o.w = f2bf(v.w);
    ((ushort4*)out)[i] = o;
  }
}

__global__ void cast4_kernel(const float* __restrict__ a0, const float* __restrict__ a1,
                             const float* __restrict__ a2, const float* __restrict__ a3,
                             u16* __restrict__ out, int n4per) {
  const float* src = blockIdx.z == 0 ? a0 : blockIdx.z == 1 ? a1 : blockIdx.z == 2 ? a2 : a3;
  u16* dst = out + (size_t)blockIdx.z * n4per * 4;
  int i = blockIdx.x * blockDim.x + threadIdx.x;
  int stride = gridDim.x * blockDim.x;
  for (; i < n4per; i += stride) {
    float4 v = ((const float4*)src)[i];
    ushort4 o;
    o.x = f2bf(v.x); o.y = f2bf(v.y); o.z = f2bf(v.z); o.w = f2bf(v.w);
    ((ushort4*)dst)[i] = o;
  }
}

// ---------------- GEMM: C[M,N] = A[M,K] * B[N,K]^T (bf16, fp32 acc) ----------------
// 128x128 tile, BK=32, 4 waves (2x2), wave = 64x64 via 4x4 16x16x32 frags.
// ZTRANS: blockIdx.z that stores C transposed (u16, [col][row]) -> for V^T.
template<int F32OUT, int ZTRANS>
__global__ __launch_bounds__(256) void gemm_bt(
    const u16* __restrict__ A,
    const u16* __restrict__ B0, const u16* __restrict__ B1, const u16* __restrict__ B2,
    void* __restrict__ C0, void* __restrict__ C1, void* __restrict__ C2,
    const float* __restrict__ bias, int K, int N) {
  const u16* B = blockIdx.z == 0 ? B0 : blockIdx.z == 1 ? B1 : B2;
  void* C = blockIdx.z == 0 ? C0 : blockIdx.z == 1 ? C1 : C2;
  __shared__ u16 As[128 * 32];
  __shared__ u16 Bs[128 * 32];
  const int tid = threadIdx.x;
  const int lane = tid & 63;
  const int wid = tid >> 6;
  const int wr = wid >> 1, wc = wid & 1;
  const int lr = lane & 15, lg = lane >> 4;
  const int row0 = blockIdx.y * 128;
  const int col0 = blockIdx.x * 128;
  const int ar = tid >> 2;
  const int ak = (tid & 3) * 8;
  const u16* Ag = A + (size_t)(row0 + ar) * K + ak;
  const u16* Bg = B + (size_t)(col0 + ar) * K + ak;
  u16* AsW = &As[wid * 512];
  u16* BsW = &Bs[wid * 512];
  f32x4 acc[4][4];
  const f32x4 fzero = {0.f, 0.f, 0.f, 0.f};
#pragma unroll
  for (int m = 0; m < 4; ++m)
#pragma unroll
    for (int n = 0; n < 4; ++n) acc[m][n] = fzero;
  for (int k0 = 0; k0 < K; k0 += 32) {
    __syncthreads();
    gload_lds16(Ag + k0, AsW);
    gload_lds16(Ag + (size_t)64 * K + k0, AsW + 2048);
    gload_lds16(Bg + k0, BsW);
    gload_lds16(Bg + (size_t)64 * K + k0, BsW + 2048);
    __syncthreads();
    short8 af[4], bfr[4];
#pragma unroll
    for (int m = 0; m < 4; ++m) af[m] = *(const short8*)&As[(wr * 64 + m * 16 + lr) * 32 + lg * 8];
#pragma unroll
    for (int n = 0; n < 4; ++n) bfr[n] = *(const short8*)&Bs[(wc * 64 + n * 16 + lr) * 32 + lg * 8];
#pragma unroll
    for (int m = 0; m < 4; ++m)
#pragma unroll
      for (int n = 0; n < 4; ++n)
        acc[m][n] = __builtin_amdgcn_mfma_f32_16x16x32_bf16(af[m], bfr[n], acc[m][n], 0, 0, 0);
  }
#pragma unroll
  for (int m = 0; m < 4; ++m) {
    const int growb = row0 + wr * 64 + m * 16 + lg * 4;
#pragma unroll
    for (int n = 0; n < 4; ++n) {
      const int gcol = col0 + wc * 64 + n * 16 + lr;
      if (ZTRANS >= 0 && blockIdx.z == ZTRANS) {
        // transposed u16 store: rows growb..growb+3 are consecutive tokens at column gcol
        ushort4 t4;
        t4.x = f2bf(acc[m][n][0]); t4.y = f2bf(acc[m][n][1]);
        t4.z = f2bf(acc[m][n][2]); t4.w = f2bf(acc[m][n][3]);
        *(ushort4*)&((u16*)C)[(size_t)gcol * TOK + growb] = t4;
      } else {
#pragma unroll
        for (int r = 0; r < 4; ++r) {
          size_t idx = (size_t)(growb + r) * N + gcol;
          if (F32OUT) ((float*)C)[idx] = acc[m][n][r] + bias[gcol];
          else ((u16*)C)[idx] = f2bf(acc[m][n][r]);
        }
      }
    }
  }
}

// ---------------- flash attention, swapped-operand (S^T = K Q^T), P in-register ----------------
// grid 1024 blocks = (qblk 16, h 16, b 4); 4 waves x 16 q-rows each; KVBLK=64.
__global__ __launch_bounds__(256) void attn_kernel(
    const u16* __restrict__ qb, const u16* __restrict__ kb, const u16* __restrict__ vtb,
    const float* __restrict__ gate, u16* __restrict__ ob) {
  // XCD-aware swizzle: group all 16 qblk of a (b,h) onto one XCD (1024 = 8 x 128)
  const int bid = blockIdx.x + (blockIdx.y << 4) + (blockIdx.z << 8);
  const int swz = (bid & 7) * 128 + (bid >> 3);
  const int qblk = swz & 15, h = (swz >> 4) & 15, b = swz >> 8;
  const int tid = threadIdx.x, lane = tid & 63, w = tid >> 6;
  const int lr = lane & 15, lg = lane >> 4;
  __shared__ u16 Kl[2][64 * 64];
  __shared__ u16 Vl[2][64 * 64];
  // Q fragment (B operand): B[e][q=lr], e contiguous per lane
  const u16* Qp = qb + (size_t)(b * SEQ + qblk * 64 + w * 16 + lr) * E_DIM + h * DK;
  const short8 bq0 = *(const short8*)&Qp[lg * 8];
  const short8 bq1 = *(const short8*)&Qp[32 + lg * 8];
  // staging: tile 64 rows x 64 el = 512 chunks(16B); 2 issues x 256 lanes.
  // LDS chunk (row, c) holds global chunk (row, c ^ (row&7))  [T2 swizzle, linear dest]
  const int r0 = tid >> 3;            // issue0 row (0..31); issue1 row = r0+32 (same row&7)
  const int cs = (tid & 7) ^ (r0 & 7);
  const u16* Kg0 = kb + (size_t)(b * SEQ + r0) * E_DIM + h * DK + cs * 8;
  const u16* Kg1 = Kg0 + (size_t)32 * E_DIM;
  const u16* Vg0 = vtb + (size_t)(h * DK + r0) * TOK + b * SEQ + cs * 8;
  const u16* Vg1 = Vg0 + (size_t)32 * TOK;
  const int ldsb = w * 512;   // wave-uniform LDS base (elements)
#define STAGE(bufi, kt) do { \
    const size_t ko = (size_t)(kt) * 64 * E_DIM; const int vo = (kt) * 64; \
    gload_lds16(Kg0 + ko, &Kl[bufi][ldsb]); \
    gload_lds16(Kg1 + ko, &Kl[bufi][2048 + ldsb]); \
    gload_lds16(Vg0 + vo, &Vl[bufi][ldsb]); \
    gload_lds16(Vg1 + vo, &Vl[bufi][2048 + ldsb]); \
  } while (0)
  f32x4 o[4];
  const f32x4 fzero = {0.f, 0.f, 0.f, 0.f};
#pragma unroll
  for (int dn = 0; dn < 4; ++dn) o[dn] = fzero;
  float mrun = -1e30f, lrun = 0.f;
  const int sw = (lr & 7) << 3;          // read-side XOR swizzle (element units)
  const int srcA = ((lg & 1) << 5) + lr; // P-shuffle source lanes: srcA, srcA+16
  const bool hi = (lg & 2) != 0;
  STAGE(0, 0);
  __syncthreads();
  int cur = 0;
  for (int kt = 0; kt < 16; ++kt) {
    if (kt < 15) STAGE(cur ^ 1, kt + 1);
    const u16* Kc = Kl[cur];
    const u16* Vc = Vl[cur];
    // S^T[k][q] = K Q^T : A = K rows (k), B = Q^T. Lane owns k = n*16+lg*4+r, q = lr.
    f32x4 sT[4];
#pragma unroll
    for (int n = 0; n < 4; ++n) {
      const int base = (n * 16 + lr) * 64;
      const short8 ka0 = *(const short8*)&Kc[base + ((lg << 3) ^ sw)];
      const short8 ka1 = *(const short8*)&Kc[base + ((32 + (lg << 3)) ^ sw)];
      sT[n] = __builtin_amdgcn_mfma_f32_16x16x32_bf16(ka0, bq0, fzero, 0, 0, 0);
      sT[n] = __builtin_amdgcn_mfma_f32_16x16x32_bf16(ka1, bq1, sT[n], 0, 0, 0);
    }
    // online softmax (per-lane scalars; q = lr)
    float mt = sT[0][0];
#pragma unroll
    for (int n = 0; n < 4; ++n)
#pragma unroll
      for (int r = 0; r < 4; ++r) mt = fmaxf(mt, sT[n][r]);
    mt = fmaxf(mt, __shfl_xor(mt, 16));
    mt = fmaxf(mt, __shfl_xor(mt, 32));
    const float mn = fmaxf(mrun, mt * 0.125f);
    const float alpha = __expf(mrun - mn);
    mrun = mn;
    float tsum = 0.f;
    u32 pk[4][2];
#pragma unroll
    for (int n = 0; n < 4; ++n) {
      const float p0 = __expf(sT[n][0] * 0.125f - mn);
      const float p1 = __expf(sT[n][1] * 0.125f - mn);
      const float p2 = __expf(sT[n][2] * 0.125f - mn);
      const float p3 = __expf(sT[n][3] * 0.125f - mn);
      tsum += (p0 + p1) + (p2 + p3);
      pk[n][0] = cvtpk_bf16(p0, p1);
      pk[n][1] = cvtpk_bf16(p2, p3);
    }
    tsum += __shfl_xor(tsum, 16);
    tsum += __shfl_xor(tsum, 32);
    lrun = lrun * alpha + tsum;
#pragma unroll
    for (int dn = 0; dn < 4; ++dn)
#pragma unroll
      for (int r = 0; r < 4; ++r) o[dn][r] *= alpha;
    // PV: O^T[d][q] += V^T P^T. A = V^T rows (d, k contig), B = P^T via shuffles.
    // B-frag lane (lg,lr), k = kh*32+lg*8+j: n_s=kh*2+(lg>>1), lg_s=(lg&1)*2+(j>>2), r_s=j&3
#pragma unroll
    for (int kh = 0; kh < 2; ++kh) {
      const int nb = kh * 2;
      union { short8 s8; u32 d[4]; } pf;
      const u32 a0 = (u32)__shfl((int)pk[nb][0], srcA);
      const u32 c0 = (u32)__shfl((int)pk[nb + 1][0], srcA);
      const u32 a1 = (u32)__shfl((int)pk[nb][1], srcA);
      const u32 c1 = (u32)__shfl((int)pk[nb + 1][1], srcA);
      const u32 a2 = (u32)__shfl((int)pk[nb][0], srcA + 16);
      const u32 c2 = (u32)__shfl((int)pk[nb + 1][0], srcA + 16);
      const u32 a3 = (u32)__shfl((int)pk[nb][1], srcA + 16);
      const u32 c3 = (u32)__shfl((int)pk[nb + 1][1], srcA + 16);
      pf.d[0] = hi ? c0 : a0;
      pf.d[1] = hi ? c1 : a1;
      pf.d[2] = hi ? c2 : a2;
      pf.d[3] = hi ? c3 : a3;
#pragma unroll
      for (int dn = 0; dn < 4; ++dn) {
        const int base = (dn * 16 + lr) * 64;
        const short8 va = *(const short8*)&Vc[base + ((((kh * 4 + lg) << 3)) ^ sw)];
        o[dn] = __builtin_amdgcn_mfma_f32_16x16x32_bf16(va, pf.s8, o[dn], 0, 0, 0);
      }
    }
    __syncthreads();
    cur ^= 1;
  }
  const float sg = 1.f / (1.f + __expf(-gate[h]));
  const float inv = sg / lrun;
  const size_t orow = (size_t)(b * SEQ + qblk * 64 + w * 16 + lr) * E_DIM + h * DK;
#pragma unroll
  for (int dn = 0; dn < 4; ++dn) {
    ushort4 o4;
    o4.x = f2bf(o[dn][0] * inv);
    o4.y = f2bf(o[dn][1] * inv);
    o4.z = f2bf(o[dn][2] * inv);
    o4.w = f2bf(o[dn][3] * inv);
    *(ushort4*)&ob[orow + dn * 16 + lg * 4] = o4;
  }
#undef STAGE
}

// ---------------- quantum statevector sim (token-independent) + relu_vec ----------------
__device__ __forceinline__ float2 cmul(float2 a, float2 b) {
  return make_float2(a.x * b.x - a.y * b.y, a.x * b.y + a.y * b.x);
}

__global__ __launch_bounds__(256) void quantum_kernel(
    const float* __restrict__ qparams, const float* __restrict__ W1,
    const float* __restrict__ bf1, float* __restrict__ relu_out) {
  __shared__ float2 st[256];
  __shared__ float pr[256];
  __shared__ float evs_s[NQB];
  const int t = threadIdx.x;
  st[t] = make_float2(t == 0 ? 1.f : 0.f, 0.f);
  for (int l = 0; l < NLAY; ++l) {
    for (int q = 0; q < NQB; ++q) {
      const int stride = 128 >> q;
      for (int g = 0; g < 3; ++g) {
        const float th = qparams[(l * NQB + q) * 3 + g] * 0.5f;
        const float c = cosf(th), sn = sinf(th);
        float2 g00, g01, g10, g11;
        if (g == 0)      { g00 = make_float2(c, 0.f); g01 = make_float2(0.f, -sn); g10 = g01; g11 = g00; }
        else if (g == 1) { g00 = make_float2(c, 0.f); g01 = make_float2(-sn, 0.f); g10 = make_float2(sn, 0.f); g11 = g00; }
        else             { g00 = make_float2(c, -sn); g01 = make_float2(0.f, 0.f); g10 = g01; g11 = make_float2(c, sn); }
        __syncthreads();
        if (t < 128) {
          const int low = t & (stride - 1);
          const int high = t >> (7 - q);
          const int i0 = (high << (8 - q)) | low;
          const int i1 = i0 + stride;
          const float2 a0 = st[i0], a1 = st[i1];
          float2 n0 = cmul(g00, a0), tmp = cmul(g01, a1);
          n0.x += tmp.x; n0.y += tmp.y;
          float2 n1 = cmul(g10, a0); tmp = cmul(g11, a1);
          n1.x += tmp.x; n1.y += tmp.y;
          st[i0] = n0; st[i1] = n1;
        }
      }
    }
    for (int ci = 0; ci < NQB; ++ci) {
      const int cb = 128 >> ci;
      const int tb = 128 >> ((ci + 1) & 7);
      __syncthreads();
      if ((t & cb) && !(t & tb)) {
        const float2 a = st[t];
        const float2 bb = st[t ^ tb];
        st[t] = bb; st[t ^ tb] = a;
      }
    }
  }
  __syncthreads();
  pr[t] = st[t].x * st[t].x + st[t].y * st[t].y;
  __syncthreads();
  if (t < NQB) {
    const int bit = 128 >> t;
    float s = 0.f;
    for (int i = 0; i < 256; ++i)
      if (i & bit) s += pr[i];
    evs_s[t] = 1.f - 2.f * s;
  }
  __syncthreads();
  for (int j = t; j < FFN_DIM; j += 256) {
    float a = bf1[j];
#pragma unroll
    for (int n = 0; n < NQB; ++n) a += evs_s[n] * W1[j * NQB + n];
    relu_out[j] = fmaxf(a, 0.f);
  }
}

// ---------------- fvec[e] = relu_vec . W2[e,:] + bf2[e]  (wave per row) ----------------
__global__ __launch_bounds__(256) void fvec_kernel(
    const float* __restrict__ W2, const float* __restrict__ bf2,
    const float* __restrict__ relu_vec, float* __restrict__ fvec) {
  const int w = threadIdx.x >> 6, lane = threadIdx.x & 63;
  const int e = blockIdx.x * 4 + w;
  const float* row = W2 + (size_t)e * FFN_DIM;
  float s = 0.f;
  for (int i = lane * 4; i < FFN_DIM; i += 256) {
    const float4 wv = *(const float4*)&row[i];
    const float4 rv = *(const float4*)&relu_vec[i];
    s += wv.x * rv.x + wv.y * rv.y + wv.z * rv.z + wv.w * rv.w;
  }
#pragma unroll
  for (int d = 32; d >= 1; d >>= 1) s += __shfl_down(s, d);
  if (lane == 0) fvec[e] = s + bf2[e];
}

// ---------------- fused: h=LN(x+ao,g1,b1); out=LN(h+fvec,g2,b2) ----------------
__global__ __launch_bounds__(256) void final_ln_kernel(
    const float* __restrict__ x, const float* __restrict__ ao, const float* __restrict__ fvec,
    const float* __restrict__ g1, const float* __restrict__ b1,
    const float* __restrict__ g2, const float* __restrict__ b2, float* __restrict__ out) {
  __shared__ float sm1[8];
  __shared__ float sm2[8];
  const size_t row = blockIdx.x;
  const int tid = threadIdx.x;
  const int w = tid >> 6, lane = tid & 63;
  const float4 xv = *(const float4*)&x[row * E_DIM + tid * 4];
  const float4 av = *(const float4*)&ao[row * E_DIM + tid * 4];
  float v0 = xv.x + av.x, v1 = xv.y + av.y, v2 = xv.z + av.z, v3 = xv.w + av.w;
  float s = v0 + v1 + v2 + v3;
  float ss = v0 * v0 + v1 * v1 + v2 * v2 + v3 * v3;
#pragma unroll
  for (int d = 32; d >= 1; d >>= 1) { s += __shfl_down(s, d); ss += __shfl_down(ss, d); }
  if (lane == 0) { sm1[w * 2] = s; sm1[w * 2 + 1] = ss; }
  __syncthreads();
  s = sm1[0] + sm1[2] + sm1[4] + sm1[6];
  ss = sm1[1] + sm1[3] + sm1[5] + sm1[7];
  const float mean = s * (1.f / 1024.f);
  const float var = ss * (1.f / 1024.f) - mean * mean;
  const float rstd = rsqrtf(var + 1e-5f);
  const float4 g1v = *(const float4*)&g1[tid * 4];
  const float4 b1v = *(const float4*)&b1[tid * 4];
  const float4 fv = *(const float4*)&fvec[tid * 4];
  float z0 = (v0 - mean) * rstd * g1v.x + b1v.x + fv.x;
  float z1 = (v1 - mean) * rstd * g1v.y + b1v.y + fv.y;
  float z2 = (v2 - mean) * rstd * g1v.z + b1v.z + fv.z;
  float z3 = (v3 - mean) * rstd * g1v.w + b1v.w + fv.w;
  float s2 = z0 + z1 + z2 + z3;
  float ss2 = z0 * z0 + z1 * z1 + z2 * z2 + z3 * z3;
#pragma unroll
  for (int d = 32; d >= 1; d >>= 1) { s2 += __shfl_down(s2, d); ss2 += __shfl_down(ss2, d); }
  if (lane == 0) { sm2[w * 2] = s2; sm2[w * 2 + 1] = ss2; }
  __syncthreads();
  s2 = sm2[0] + sm2[2] + sm2[4] + sm2[6];
  ss2 = sm2[1] + sm2[3] + sm2[5] + sm2[7];
  const float mean2 = s2 * (1.f / 1024.f);
  const float var2 = ss2 * (1.f / 1024.f) - mean2 * mean2;
  const float rstd2 = rsqrtf(var2 + 1e-5f);
  const float4 g2v = *(const float4*)&g2[tid * 4];
  const float4 b2v = *(const float4*)&b2[tid * 4];
  float4 ov;
  ov.x = (z0 - mean2) * rstd2 * g2v.x + b2v.x;
  ov.y = (z1 - mean2) * rstd2 * g2v.y + b2v.y;
  ov.z = (z2 - mean2) * rstd2 * g2v.z + b2v.z;
  ov.w = (z3 - mean2) * rstd2 * g2v.w + b2v.w;
  *(float4*)&out[row * E_DIM + tid * 4] = ov;
}

extern "C" void kernel_launch(void* const* d_in, const int* in_sizes, int n_in,
                              void* d_out, int out_size, void* d_ws, size_t ws_size,
                              hipStream_t stream) {
  (void)in_sizes; (void)n_in; (void)out_size; (void)ws_size;
  const float* x       = (const float*)d_in[0];
  const float* Wq      = (const float*)d_in[1];
  const float* Wk      = (const float*)d_in[2];
  const float* Wv      = (const float*)d_in[3];
  const float* Wo      = (const float*)d_in[4];
  const float* bo      = (const float*)d_in[5];
  const float* gate    = (const float*)d_in[6];
  const float* g1      = (const float*)d_in[7];
  const float* b1      = (const float*)d_in[8];
  const float* g2      = (const float*)d_in[9];
  const float* b2      = (const float*)d_in[10];
  // d_in[11] Wi, d_in[12] bi: computed-but-unused in reference -> skipped
  const float* qparams = (const float*)d_in[13];
  const float* W1      = (const float*)d_in[14];
  const float* bf1     = (const float*)d_in[15];
  const float* W2      = (const float*)d_in[16];
  const float* bf2     = (const float*)d_in[17];

  char* ws = (char*)d_ws;
  u16* xb        = (u16*)(ws + 0);          // 8 MB
  u16* wqb       = (u16*)(ws + 8388608);    // 2 MB each
  u16* wkb       = (u16*)(ws + 10485760);
  u16* wvb       = (u16*)(ws + 12582912);
  u16* wob       = (u16*)(ws + 14680064);
  u16* qb        = (u16*)(ws + 16777216);   // 8 MB
  u16* kb        = (u16*)(ws + 25165824);   // 8 MB
  u16* vtb       = (u16*)(ws + 33554432);   // 8 MB, layout [e][token]
  u16* ab        = (u16*)(ws + 41943040);   // 8 MB
  float* ao      = (float*)(ws + 50331648); // 16 MB
  float* relu_vec= (float*)(ws + 67108864); // 16 KB
  float* fvec    = (float*)(ws + 67125248); // 4 KB

  cast_kernel<<<2048, 256, 0, stream>>>(x, xb, TOK * E_DIM / 4);
  cast4_kernel<<<dim3(1024, 1, 4), 256, 0, stream>>>(Wq, Wk, Wv, Wo, wqb, E_DIM * E_DIM / 4);
  quantum_kernel<<<1, 256, 0, stream>>>(qparams, W1, bf1, relu_vec);
  fvec_kernel<<<256, 256, 0, stream>>>(W2, bf2, relu_vec, fvec);
  // QKV: z=0 -> qb (row-major), z=1 -> kb (row-major), z=2 -> vtb (transposed)
  gemm_bt<0, 2><<<dim3(8, 32, 3), 256, 0, stream>>>(xb, wqb, wkb, wvb, qb, kb, vtb, nullptr, E_DIM, E_DIM);
  attn_kernel<<<dim3(16, 16, 4), 256, 0, stream>>>(qb, kb, vtb, gate, ab);
  gemm_bt<1, -1><<<dim3(8, 32, 1), 256, 0, stream>>>(ab, wob, wob, wob, ao, ao, ao, bo, E_DIM, E_DIM);
  final_ln_kernel<<<4096, 256, 0, stream>>>(x, ao, fvec, g1, b1, g2, b2, (float*)d_out);
}

// Round 3
// 252.990 us; speedup vs baseline: 1.3355x; 1.1766x over previous
//
#include <hip/hip_runtime.h>

#define E_DIM 1024
#define SEQ 1024
#define BATCH 4
#define NHEAD 16
#define DK 64
#define TOK 4096
#define FFN_DIM 4096
#define NQB 8
#define NLAY 4

typedef __attribute__((ext_vector_type(8))) short short8;
typedef __attribute__((ext_vector_type(4))) float f32x4;
typedef unsigned short u16;
typedef unsigned int u32;

__device__ __forceinline__ u16 f2bf(float f) {
  union { float f; unsigned u; } v; v.f = f;
  unsigned r = v.u + 0x7fffu + ((v.u >> 16) & 1u);
  return (u16)(r >> 16);
}

__device__ __forceinline__ u32 cvtpk_bf16(float lo, float hi) {
  u32 r;
  asm("v_cvt_pk_bf16_f32 %0, %1, %2" : "=v"(r) : "v"(lo), "v"(hi));
  return r;
}

__device__ __forceinline__ void gload_lds16(const u16* g, u16* l) {
  __builtin_amdgcn_global_load_lds((const __attribute__((address_space(1))) unsigned int*)g,
                                   (__attribute__((address_space(3))) unsigned int*)l, 16, 0, 0);
}

// ---------------- casts ----------------
__global__ void cast_kernel(const float* __restrict__ in, u16* __restrict__ out, int n4) {
  int i = blockIdx.x * blockDim.x + threadIdx.x;
  int stride = gridDim.x * blockDim.x;
  for (; i < n4; i += stride) {
    float4 v = ((const float4*)in)[i];
    ushort4 o;
    o.x = f2bf(v.x); o.y = f2bf(v.y); o.z = f2bf(v.z); o.w = f2bf(v.w);
    ((ushort4*)out)[i] = o;
  }
}

__global__ void cast4_kernel(const float* __restrict__ a0, const float* __restrict__ a1,
                             const float* __restrict__ a2, const float* __restrict__ a3,
                             u16* __restrict__ out, int n4per) {
  const float* src = blockIdx.z == 0 ? a0 : blockIdx.z == 1 ? a1 : blockIdx.z == 2 ? a2 : a3;
  u16* dst = out + (size_t)blockIdx.z * n4per * 4;
  int i = blockIdx.x * blockDim.x + threadIdx.x;
  int stride = gridDim.x * blockDim.x;
  for (; i < n4per; i += stride) {
    float4 v = ((const float4*)src)[i];
    ushort4 o;
    o.x = f2bf(v.x); o.y = f2bf(v.y); o.z = f2bf(v.z); o.w = f2bf(v.w);
    ((ushort4*)dst)[i] = o;
  }
}

// ---------------- GEMM: C[M,N] = A[M,K] * B[N,K]^T (bf16, fp32 acc) ----------------
template<int F32OUT, int ZTRANS>
__global__ __launch_bounds__(256) void gemm_bt(
    const u16* __restrict__ A,
    const u16* __restrict__ B0, const u16* __restrict__ B1, const u16* __restrict__ B2,
    void* __restrict__ C0, void* __restrict__ C1, void* __restrict__ C2,
    const float* __restrict__ bias, int K, int N) {
  const u16* B = blockIdx.z == 0 ? B0 : blockIdx.z == 1 ? B1 : B2;
  void* C = blockIdx.z == 0 ? C0 : blockIdx.z == 1 ? C1 : C2;
  __shared__ u16 As[128 * 32];
  __shared__ u16 Bs[128 * 32];
  const int tid = threadIdx.x;
  const int lane = tid & 63;
  const int wid = tid >> 6;
  const int wr = wid >> 1, wc = wid & 1;
  const int lr = lane & 15, lg = lane >> 4;
  const int row0 = blockIdx.y * 128;
  const int col0 = blockIdx.x * 128;
  const int ar = tid >> 2;
  const int ak = (tid & 3) * 8;
  const u16* Ag = A + (size_t)(row0 + ar) * K + ak;
  const u16* Bg = B + (size_t)(col0 + ar) * K + ak;
  u16* AsW = &As[wid * 512];
  u16* BsW = &Bs[wid * 512];
  f32x4 acc[4][4];
  const f32x4 fzero = {0.f, 0.f, 0.f, 0.f};
#pragma unroll
  for (int m = 0; m < 4; ++m)
#pragma unroll
    for (int n = 0; n < 4; ++n) acc[m][n] = fzero;
  for (int k0 = 0; k0 < K; k0 += 32) {
    __syncthreads();
    gload_lds16(Ag + k0, AsW);
    gload_lds16(Ag + (size_t)64 * K + k0, AsW + 2048);
    gload_lds16(Bg + k0, BsW);
    gload_lds16(Bg + (size_t)64 * K + k0, BsW + 2048);
    __syncthreads();
    short8 af[4], bfr[4];
#pragma unroll
    for (int m = 0; m < 4; ++m) af[m] = *(const short8*)&As[(wr * 64 + m * 16 + lr) * 32 + lg * 8];
#pragma unroll
    for (int n = 0; n < 4; ++n) bfr[n] = *(const short8*)&Bs[(wc * 64 + n * 16 + lr) * 32 + lg * 8];
#pragma unroll
    for (int m = 0; m < 4; ++m)
#pragma unroll
      for (int n = 0; n < 4; ++n)
        acc[m][n] = __builtin_amdgcn_mfma_f32_16x16x32_bf16(af[m], bfr[n], acc[m][n], 0, 0, 0);
  }
#pragma unroll
  for (int m = 0; m < 4; ++m) {
    const int growb = row0 + wr * 64 + m * 16 + lg * 4;
#pragma unroll
    for (int n = 0; n < 4; ++n) {
      const int gcol = col0 + wc * 64 + n * 16 + lr;
      if (ZTRANS >= 0 && blockIdx.z == ZTRANS) {
        ushort4 t4;
        t4.x = f2bf(acc[m][n][0]); t4.y = f2bf(acc[m][n][1]);
        t4.z = f2bf(acc[m][n][2]); t4.w = f2bf(acc[m][n][3]);
        *(ushort4*)&((u16*)C)[(size_t)gcol * TOK + growb] = t4;
      } else {
#pragma unroll
        for (int r = 0; r < 4; ++r) {
          size_t idx = (size_t)(growb + r) * N + gcol;
          if (F32OUT) ((float*)C)[idx] = acc[m][n][r] + bias[gcol];
          else ((u16*)C)[idx] = f2bf(acc[m][n][r]);
        }
      }
    }
  }
}

// ---------------- flash attention, swapped-operand (S^T = K Q^T), P in-register ----------------
__global__ __launch_bounds__(256) void attn_kernel(
    const u16* __restrict__ qb, const u16* __restrict__ kb, const u16* __restrict__ vtb,
    const float* __restrict__ gate, u16* __restrict__ ob) {
  const int bid = blockIdx.x + (blockIdx.y << 4) + (blockIdx.z << 8);
  const int swz = (bid & 7) * 128 + (bid >> 3);
  const int qblk = swz & 15, h = (swz >> 4) & 15, b = swz >> 8;
  const int tid = threadIdx.x, lane = tid & 63, w = tid >> 6;
  const int lr = lane & 15, lg = lane >> 4;
  __shared__ u16 Kl[2][64 * 64];
  __shared__ u16 Vl[2][64 * 64];
  const u16* Qp = qb + (size_t)(b * SEQ + qblk * 64 + w * 16 + lr) * E_DIM + h * DK;
  const short8 bq0 = *(const short8*)&Qp[lg * 8];
  const short8 bq1 = *(const short8*)&Qp[32 + lg * 8];
  const int r0 = tid >> 3;
  const int cs = (tid & 7) ^ (r0 & 7);
  const u16* Kg0 = kb + (size_t)(b * SEQ + r0) * E_DIM + h * DK + cs * 8;
  const u16* Kg1 = Kg0 + (size_t)32 * E_DIM;
  const u16* Vg0 = vtb + (size_t)(h * DK + r0) * TOK + b * SEQ + cs * 8;
  const u16* Vg1 = Vg0 + (size_t)32 * TOK;
  const int ldsb = w * 512;
#define STAGE(bufi, kt) do { \
    const size_t ko = (size_t)(kt) * 64 * E_DIM; const int vo = (kt) * 64; \
    gload_lds16(Kg0 + ko, &Kl[bufi][ldsb]); \
    gload_lds16(Kg1 + ko, &Kl[bufi][2048 + ldsb]); \
    gload_lds16(Vg0 + vo, &Vl[bufi][ldsb]); \
    gload_lds16(Vg1 + vo, &Vl[bufi][2048 + ldsb]); \
  } while (0)
  f32x4 o[4];
  const f32x4 fzero = {0.f, 0.f, 0.f, 0.f};
#pragma unroll
  for (int dn = 0; dn < 4; ++dn) o[dn] = fzero;
  float mrun = -1e30f, lrun = 0.f;
  const int sw = (lr & 7) << 3;
  const int srcA = ((lg & 1) << 5) + lr;
  const bool hi = (lg & 2) != 0;
  STAGE(0, 0);
  __syncthreads();
  int cur = 0;
  for (int kt = 0; kt < 16; ++kt) {
    if (kt < 15) STAGE(cur ^ 1, kt + 1);
    const u16* Kc = Kl[cur];
    const u16* Vc = Vl[cur];
    f32x4 sT[4];
#pragma unroll
    for (int n = 0; n < 4; ++n) {
      const int base = (n * 16 + lr) * 64;
      const short8 ka0 = *(const short8*)&Kc[base + ((lg << 3) ^ sw)];
      const short8 ka1 = *(const short8*)&Kc[base + ((32 + (lg << 3)) ^ sw)];
      sT[n] = __builtin_amdgcn_mfma_f32_16x16x32_bf16(ka0, bq0, fzero, 0, 0, 0);
      sT[n] = __builtin_amdgcn_mfma_f32_16x16x32_bf16(ka1, bq1, sT[n], 0, 0, 0);
    }
    float mt = sT[0][0];
#pragma unroll
    for (int n = 0; n < 4; ++n)
#pragma unroll
      for (int r = 0; r < 4; ++r) mt = fmaxf(mt, sT[n][r]);
    mt = fmaxf(mt, __shfl_xor(mt, 16));
    mt = fmaxf(mt, __shfl_xor(mt, 32));
    const float mn = fmaxf(mrun, mt * 0.125f);
    const float alpha = __expf(mrun - mn);
    mrun = mn;
    float tsum = 0.f;
    u32 pk[4][2];
#pragma unroll
    for (int n = 0; n < 4; ++n) {
      const float p0 = __expf(sT[n][0] * 0.125f - mn);
      const float p1 = __expf(sT[n][1] * 0.125f - mn);
      const float p2 = __expf(sT[n][2] * 0.125f - mn);
      const float p3 = __expf(sT[n][3] * 0.125f - mn);
      tsum += (p0 + p1) + (p2 + p3);
      pk[n][0] = cvtpk_bf16(p0, p1);
      pk[n][1] = cvtpk_bf16(p2, p3);
    }
    tsum += __shfl_xor(tsum, 16);
    tsum += __shfl_xor(tsum, 32);
    lrun = lrun * alpha + tsum;
#pragma unroll
    for (int dn = 0; dn < 4; ++dn)
#pragma unroll
      for (int r = 0; r < 4; ++r) o[dn][r] *= alpha;
#pragma unroll
    for (int kh = 0; kh < 2; ++kh) {
      const int nb = kh * 2;
      union { short8 s8; u32 d[4]; } pf;
      const u32 a0 = (u32)__shfl((int)pk[nb][0], srcA);
      const u32 c0 = (u32)__shfl((int)pk[nb + 1][0], srcA);
      const u32 a1 = (u32)__shfl((int)pk[nb][1], srcA);
      const u32 c1 = (u32)__shfl((int)pk[nb + 1][1], srcA);
      const u32 a2 = (u32)__shfl((int)pk[nb][0], srcA + 16);
      const u32 c2 = (u32)__shfl((int)pk[nb + 1][0], srcA + 16);
      const u32 a3 = (u32)__shfl((int)pk[nb][1], srcA + 16);
      const u32 c3 = (u32)__shfl((int)pk[nb + 1][1], srcA + 16);
      pf.d[0] = hi ? c0 : a0;
      pf.d[1] = hi ? c1 : a1;
      pf.d[2] = hi ? c2 : a2;
      pf.d[3] = hi ? c3 : a3;
#pragma unroll
      for (int dn = 0; dn < 4; ++dn) {
        const int base = (dn * 16 + lr) * 64;
        const short8 va = *(const short8*)&Vc[base + ((((kh * 4 + lg) << 3)) ^ sw)];
        o[dn] = __builtin_amdgcn_mfma_f32_16x16x32_bf16(va, pf.s8, o[dn], 0, 0, 0);
      }
    }
    __syncthreads();
    cur ^= 1;
  }
  const float sg = 1.f / (1.f + __expf(-gate[h]));
  const float inv = sg / lrun;
  const size_t orow = (size_t)(b * SEQ + qblk * 64 + w * 16 + lr) * E_DIM + h * DK;
#pragma unroll
  for (int dn = 0; dn < 4; ++dn) {
    ushort4 o4;
    o4.x = f2bf(o[dn][0] * inv);
    o4.y = f2bf(o[dn][1] * inv);
    o4.z = f2bf(o[dn][2] * inv);
    o4.w = f2bf(o[dn][3] * inv);
    *(ushort4*)&ob[orow + dn * 16 + lg * 4] = o4;
  }
#undef STAGE
}

// ---------------- quantum sim: 1 wave, statevector in registers, shfl-based ----------------
// index i (8 bits): lane = i>>2 (bits 7:2), reg = i&3 (bits 1:0). qubit q <-> bit (7-q).
__global__ __launch_bounds__(256) void quantum_kernel(
    const float* __restrict__ qparams, const float* __restrict__ W1,
    const float* __restrict__ bf1, float* __restrict__ relu_out) {
  __shared__ float csl[96], snl[96];
  __shared__ float evs_s[NQB];
  const int t = threadIdx.x;
  if (t < NLAY * NQB * 3) {
    const float th = qparams[t] * 0.5f;
    csl[t] = cosf(th);
    snl[t] = sinf(th);
  }
  __syncthreads();
  if (t < 64) {
    const int lane = t;
    float2 a[4];
    a[0] = make_float2(lane == 0 ? 1.f : 0.f, 0.f);
    a[1] = make_float2(0.f, 0.f);
    a[2] = make_float2(0.f, 0.f);
    a[3] = make_float2(0.f, 0.f);
#pragma unroll
    for (int l = 0; l < NLAY; ++l) {
#pragma unroll
      for (int q = 0; q < NQB; ++q) {
        const int pi = (l * NQB + q) * 3;
        const float cx = csl[pi],     sx = snl[pi];
        const float cy = csl[pi + 1], sy = snl[pi + 1];
        const float cz = csl[pi + 2], sz = snl[pi + 2];
        if (q < 6) {
          const int m = 1 << (5 - q);
          const int b = (lane >> (5 - q)) & 1;
          // Rx: new = c*self - i*s*partner (symmetric in b)
#pragma unroll
          for (int r = 0; r < 4; ++r) {
            const float px = __shfl_xor(a[r].x, m);
            const float py = __shfl_xor(a[r].y, m);
            a[r] = make_float2(cx * a[r].x + sx * py, cx * a[r].y - sx * px);
          }
          // Ry: b=0: c*self - s*partner ; b=1: c*self + s*partner
          const float sgy = b ? sy : -sy;
#pragma unroll
          for (int r = 0; r < 4; ++r) {
            const float px = __shfl_xor(a[r].x, m);
            const float py = __shfl_xor(a[r].y, m);
            a[r] = make_float2(cy * a[r].x + sgy * px, cy * a[r].y + sgy * py);
          }
          // Rz: b=0: e^{-i th/2}, b=1: e^{+i th/2}
          const float sgz = b ? -sz : sz;
#pragma unroll
          for (int r = 0; r < 4; ++r)
            a[r] = make_float2(cz * a[r].x + sgz * a[r].y, cz * a[r].y - sgz * a[r].x);
        } else if (q == 6) {
          // pairs (0,2),(1,3)
#pragma unroll
          for (int r = 0; r < 2; ++r) {
            float2 lo = a[r], hiv = a[r + 2];
            a[r]     = make_float2(cx * lo.x + sx * hiv.y, cx * lo.y - sx * hiv.x);
            a[r + 2] = make_float2(cx * hiv.x + sx * lo.y, cx * hiv.y - sx * lo.x);
          }
#pragma unroll
          for (int r = 0; r < 2; ++r) {
            float2 lo = a[r], hiv = a[r + 2];
            a[r]     = make_float2(cy * lo.x - sy * hiv.x, cy * lo.y - sy * hiv.y);
            a[r + 2] = make_float2(sy * lo.x + cy * hiv.x, sy * lo.y + cy * hiv.y);
          }
#pragma unroll
          for (int r = 0; r < 2; ++r) {
            float2 lo = a[r], hiv = a[r + 2];
            a[r]     = make_float2(cz * lo.x + sz * lo.y, cz * lo.y - sz * lo.x);
            a[r + 2] = make_float2(cz * hiv.x - sz * hiv.y, cz * hiv.y + sz * hiv.x);
          }
        } else {
          // pairs (0,1),(2,3)
#pragma unroll
          for (int r = 0; r < 4; r += 2) {
            float2 lo = a[r], hiv = a[r + 1];
            a[r]     = make_float2(cx * lo.x + sx * hiv.y, cx * lo.y - sx * hiv.x);
            a[r + 1] = make_float2(cx * hiv.x + sx * lo.y, cx * hiv.y - sx * lo.x);
          }
#pragma unroll
          for (int r = 0; r < 4; r += 2) {
            float2 lo = a[r], hiv = a[r + 1];
            a[r]     = make_float2(cy * lo.x - sy * hiv.x, cy * lo.y - sy * hiv.y);
            a[r + 1] = make_float2(sy * lo.x + cy * hiv.x, sy * lo.y + cy * hiv.y);
          }
#pragma unroll
          for (int r = 0; r < 4; r += 2) {
            float2 lo = a[r], hiv = a[r + 1];
            a[r]     = make_float2(cz * lo.x + sz * lo.y, cz * lo.y - sz * lo.x);
            a[r + 1] = make_float2(cz * hiv.x - sz * hiv.y, cz * hiv.y + sz * hiv.x);
          }
        }
      }
      // CNOT chain: (0,1)..(6,7),(7,0). control q c -> bit 7-c, target q t -> bit 7-t.
#pragma unroll
      for (int i = 0; i < 5; ++i) {
        const int cbit = 5 - i;          // lane bit of control
        const int tmask = 1 << (4 - i);  // lane mask of target
        const int ctrl = (lane >> cbit) & 1;
#pragma unroll
        for (int r = 0; r < 4; ++r) {
          const float px = __shfl_xor(a[r].x, tmask);
          const float py = __shfl_xor(a[r].y, tmask);
          if (ctrl) a[r] = make_float2(px, py);
        }
      }
      // i=5: control lane bit0, target reg bit1
      if (lane & 1) {
        float2 t0 = a[0]; a[0] = a[2]; a[2] = t0;
        float2 t1 = a[1]; a[1] = a[3]; a[3] = t1;
      }
      // i=6: control reg bit1, target reg bit0: swap a2<->a3
      { float2 tt = a[2]; a[2] = a[3]; a[3] = tt; }
      // (7,0): control reg bit0, target lane bit5: swap a1,a3 across lane^32
      a[1].x = __shfl_xor(a[1].x, 32); a[1].y = __shfl_xor(a[1].y, 32);
      a[3].x = __shfl_xor(a[3].x, 32); a[3].y = __shfl_xor(a[3].y, 32);
    }
    const float p0 = a[0].x * a[0].x + a[0].y * a[0].y;
    const float p1 = a[1].x * a[1].x + a[1].y * a[1].y;
    const float p2 = a[2].x * a[2].x + a[2].y * a[2].y;
    const float p3 = a[3].x * a[3].x + a[3].y * a[3].y;
    const float ptot = (p0 + p1) + (p2 + p3);
    float ev[8];
#pragma unroll
    for (int q = 0; q < 6; ++q) ev[q] = ((lane >> (5 - q)) & 1) ? ptot : 0.f;
    ev[6] = p2 + p3;
    ev[7] = p1 + p3;
#pragma unroll
    for (int d = 1; d < 64; d <<= 1)
#pragma unroll
      for (int q = 0; q < 8; ++q) ev[q] += __shfl_xor(ev[q], d);
    if (lane == 0) {
#pragma unroll
      for (int q = 0; q < 8; ++q) evs_s[q] = 1.f - 2.f * ev[q];
    }
  }
  __syncthreads();
  float e0 = evs_s[0], e1 = evs_s[1], e2 = evs_s[2], e3 = evs_s[3];
  float e4 = evs_s[4], e5 = evs_s[5], e6 = evs_s[6], e7 = evs_s[7];
  for (int j = t; j < FFN_DIM; j += 256) {
    const float4 w0 = *(const float4*)&W1[j * NQB];
    const float4 w1 = *(const float4*)&W1[j * NQB + 4];
    float acc = bf1[j];
    acc += e0 * w0.x + e1 * w0.y + e2 * w0.z + e3 * w0.w;
    acc += e4 * w1.x + e5 * w1.y + e6 * w1.z + e7 * w1.w;
    relu_out[j] = fmaxf(acc, 0.f);
  }
}

// ---------------- fvec[e] = relu_vec . W2[e,:] + bf2[e]  (wave per row) ----------------
__global__ __launch_bounds__(256) void fvec_kernel(
    const float* __restrict__ W2, const float* __restrict__ bf2,
    const float* __restrict__ relu_vec, float* __restrict__ fvec) {
  const int w = threadIdx.x >> 6, lane = threadIdx.x & 63;
  const int e = blockIdx.x * 4 + w;
  const float* row = W2 + (size_t)e * FFN_DIM;
  float s = 0.f;
  for (int i = lane * 4; i < FFN_DIM; i += 256) {
    const float4 wv = *(const float4*)&row[i];
    const float4 rv = *(const float4*)&relu_vec[i];
    s += wv.x * rv.x + wv.y * rv.y + wv.z * rv.z + wv.w * rv.w;
  }
#pragma unroll
  for (int d = 32; d >= 1; d >>= 1) s += __shfl_down(s, d);
  if (lane == 0) fvec[e] = s + bf2[e];
}

// ---------------- fused: h=LN(x+ao,g1,b1); out=LN(h+fvec,g2,b2) ----------------
__global__ __launch_bounds__(256) void final_ln_kernel(
    const float* __restrict__ x, const float* __restrict__ ao, const float* __restrict__ fvec,
    const float* __restrict__ g1, const float* __restrict__ b1,
    const float* __restrict__ g2, const float* __restrict__ b2, float* __restrict__ out) {
  __shared__ float sm1[8];
  __shared__ float sm2[8];
  const size_t row = blockIdx.x;
  const int tid = threadIdx.x;
  const int w = tid >> 6, lane = tid & 63;
  const float4 xv = *(const float4*)&x[row * E_DIM + tid * 4];
  const float4 av = *(const float4*)&ao[row * E_DIM + tid * 4];
  float v0 = xv.x + av.x, v1 = xv.y + av.y, v2 = xv.z + av.z, v3 = xv.w + av.w;
  float s = v0 + v1 + v2 + v3;
  float ss = v0 * v0 + v1 * v1 + v2 * v2 + v3 * v3;
#pragma unroll
  for (int d = 32; d >= 1; d >>= 1) { s += __shfl_down(s, d); ss += __shfl_down(ss, d); }
  if (lane == 0) { sm1[w * 2] = s; sm1[w * 2 + 1] = ss; }
  __syncthreads();
  s = sm1[0] + sm1[2] + sm1[4] + sm1[6];
  ss = sm1[1] + sm1[3] + sm1[5] + sm1[7];
  const float mean = s * (1.f / 1024.f);
  const float var = ss * (1.f / 1024.f) - mean * mean;
  const float rstd = rsqrtf(var + 1e-5f);
  const float4 g1v = *(const float4*)&g1[tid * 4];
  const float4 b1v = *(const float4*)&b1[tid * 4];
  const float4 fv = *(const float4*)&fvec[tid * 4];
  float z0 = (v0 - mean) * rstd * g1v.x + b1v.x + fv.x;
  float z1 = (v1 - mean) * rstd * g1v.y + b1v.y + fv.y;
  float z2 = (v2 - mean) * rstd * g1v.z + b1v.z + fv.z;
  float z3 = (v3 - mean) * rstd * g1v.w + b1v.w + fv.w;
  float s2 = z0 + z1 + z2 + z3;
  float ss2 = z0 * z0 + z1 * z1 + z2 * z2 + z3 * z3;
#pragma unroll
  for (int d = 32; d >= 1; d >>= 1) { s2 += __shfl_down(s2, d); ss2 += __shfl_down(ss2, d); }
  if (lane == 0) { sm2[w * 2] = s2; sm2[w * 2 + 1] = ss2; }
  __syncthreads();
  s2 = sm2[0] + sm2[2] + sm2[4] + sm2[6];
  ss2 = sm2[1] + sm2[3] + sm2[5] + sm2[7];
  const float mean2 = s2 * (1.f / 1024.f);
  const float var2 = ss2 * (1.f / 1024.f) - mean2 * mean2;
  const float rstd2 = rsqrtf(var2 + 1e-5f);
  const float4 g2v = *(const float4*)&g2[tid * 4];
  const float4 b2v = *(const float4*)&b2[tid * 4];
  float4 ov;
  ov.x = (z0 - mean2) * rstd2 * g2v.x + b2v.x;
  ov.y = (z1 - mean2) * rstd2 * g2v.y + b2v.y;
  ov.z = (z2 - mean2) * rstd2 * g2v.z + b2v.z;
  ov.w = (z3 - mean2) * rstd2 * g2v.w + b2v.w;
  *(float4*)&out[row * E_DIM + tid * 4] = ov;
}

extern "C" void kernel_launch(void* const* d_in, const int* in_sizes, int n_in,
                              void* d_out, int out_size, void* d_ws, size_t ws_size,
                              hipStream_t stream) {
  (void)in_sizes; (void)n_in; (void)out_size; (void)ws_size;
  const float* x       = (const float*)d_in[0];
  const float* Wq      = (const float*)d_in[1];
  const float* Wk      = (const float*)d_in[2];
  const float* Wv      = (const float*)d_in[3];
  const float* Wo      = (const float*)d_in[4];
  const float* bo      = (const float*)d_in[5];
  const float* gate    = (const float*)d_in[6];
  const float* g1      = (const float*)d_in[7];
  const float* b1      = (const float*)d_in[8];
  const float* g2      = (const float*)d_in[9];
  const float* b2      = (const float*)d_in[10];
  const float* qparams = (const float*)d_in[13];
  const float* W1      = (const float*)d_in[14];
  const float* bf1     = (const float*)d_in[15];
  const float* W2      = (const float*)d_in[16];
  const float* bf2     = (const float*)d_in[17];

  char* ws = (char*)d_ws;
  u16* xb        = (u16*)(ws + 0);          // 8 MB
  u16* wqb       = (u16*)(ws + 8388608);    // 2 MB each
  u16* wkb       = (u16*)(ws + 10485760);
  u16* wvb       = (u16*)(ws + 12582912);
  u16* wob       = (u16*)(ws + 14680064);
  u16* qb        = (u16*)(ws + 16777216);   // 8 MB
  u16* kb        = (u16*)(ws + 25165824);   // 8 MB
  u16* vtb       = (u16*)(ws + 33554432);   // 8 MB, layout [e][token]
  u16* ab        = (u16*)(ws + 41943040);   // 8 MB
  float* ao      = (float*)(ws + 50331648); // 16 MB
  float* relu_vec= (float*)(ws + 67108864); // 16 KB
  float* fvec    = (float*)(ws + 67125248); // 4 KB

  cast_kernel<<<2048, 256, 0, stream>>>(x, xb, TOK * E_DIM / 4);
  cast4_kernel<<<dim3(1024, 1, 4), 256, 0, stream>>>(Wq, Wk, Wv, Wo, wqb, E_DIM * E_DIM / 4);
  quantum_kernel<<<1, 256, 0, stream>>>(qparams, W1, bf1, relu_vec);
  fvec_kernel<<<256, 256, 0, stream>>>(W2, bf2, relu_vec, fvec);
  gemm_bt<0, 2><<<dim3(8, 32, 3), 256, 0, stream>>>(xb, wqb, wkb, wvb, qb, kb, vtb, nullptr, E_DIM, E_DIM);
  attn_kernel<<<dim3(16, 16, 4), 256, 0, stream>>>(qb, kb, vtb, gate, ab);
  gemm_bt<1, -1><<<dim3(8, 32, 1), 256, 0, stream>>>(ab, wob, wob, wob, ao, ao, ao, bo, E_DIM, E_DIM);
  final_ln_kernel<<<4096, 256, 0, stream>>>(x, ao, fvec, g1, b1, g2, b2, (float*)d_out);
}